// Round 1
// baseline (865.516 us; speedup 1.0000x reference)
//
#include <hip/hip_runtime.h>
#include <hip/hip_bf16.h>
#include <math.h>

typedef unsigned short u16;
typedef __attribute__((ext_vector_type(8))) short bf16x8;
typedef __attribute__((ext_vector_type(4))) float f32x4;

#define MFMA_BF16 __builtin_amdgcn_mfma_f32_16x16x32_bf16

__device__ __forceinline__ u16 f2bf(float f){
  union { float f; unsigned u; } v; v.f = f;
  unsigned r = v.u + 0x7FFFu + ((v.u >> 16) & 1u);
  return (u16)(r >> 16);
}

// ---------------- weight prep: fp32 [K][N] -> bf16 [N][K] ----------------
__global__ void k_transpose(const float* __restrict__ src, u16* __restrict__ dst, int K, int N){
  int idx = blockIdx.x*256 + threadIdx.x;
  if (idx >= K*N) return;
  int n = idx / K, k = idx - n*K;
  dst[idx] = f2bf(src[(size_t)k*N + n]);
}

__global__ void k_concat_bias(const float* __restrict__ a, const float* __restrict__ b,
                              const float* __restrict__ c, float* __restrict__ o){
  int i = threadIdx.x;  // 768 threads
  o[i] = i < 256 ? a[i] : (i < 512 ? b[i-256] : c[i-512]);
}

// ------------- LN1 + cyclic shift + window partition -> bf16 -------------
// out row m: b = m>>12, win = (m>>6)&63, p = m&63 ; reads original token
// h = (wh*8+r+4)&63, w = (ww*8+c+4)&63
__global__ __launch_bounds__(256) void k_ln1(const float* __restrict__ x, const float* __restrict__ g,
                                             const float* __restrict__ b, u16* __restrict__ out){
  int lane = threadIdx.x & 63;
  int m = blockIdx.x*4 + (threadIdx.x >> 6);
  int bi = m >> 12, win = (m >> 6) & 63, p = m & 63;
  int h = ((win >> 3)*8 + (p >> 3) + 4) & 63;
  int w = ((win & 7)*8 + (p & 7) + 4) & 63;
  float4 v = ((const float4*)(x + ((size_t)bi*4096 + h*64 + w)*256))[lane];
  float s = v.x+v.y+v.z+v.w, sq = v.x*v.x+v.y*v.y+v.z*v.z+v.w*v.w;
  for (int off=32; off; off>>=1){ s += __shfl_xor(s, off); sq += __shfl_xor(sq, off); }
  float mean = s*(1.f/256.f);
  float inv = rsqrtf(sq*(1.f/256.f) - mean*mean + 1e-5f);
  float4 gg = ((const float4*)g)[lane], bb = ((const float4*)b)[lane];
  ushort4 o;
  o.x = f2bf((v.x-mean)*inv*gg.x + bb.x);
  o.y = f2bf((v.y-mean)*inv*gg.y + bb.y);
  o.z = f2bf((v.z-mean)*inv*gg.z + bb.z);
  o.w = f2bf((v.w-mean)*inv*gg.w + bb.w);
  ((ushort4*)(out + (size_t)m*256))[lane] = o;
}

// ---------------- LN2 (no gather) -> bf16 ----------------
__global__ __launch_bounds__(256) void k_ln2(const float* __restrict__ x, const float* __restrict__ g,
                                             const float* __restrict__ b, u16* __restrict__ out){
  int lane = threadIdx.x & 63;
  int m = blockIdx.x*4 + (threadIdx.x >> 6);
  float4 v = ((const float4*)(x + (size_t)m*256))[lane];
  float s = v.x+v.y+v.z+v.w, sq = v.x*v.x+v.y*v.y+v.z*v.z+v.w*v.w;
  for (int off=32; off; off>>=1){ s += __shfl_xor(s, off); sq += __shfl_xor(sq, off); }
  float mean = s*(1.f/256.f);
  float inv = rsqrtf(sq*(1.f/256.f) - mean*mean + 1e-5f);
  float4 gg = ((const float4*)g)[lane], bb = ((const float4*)b)[lane];
  ushort4 o;
  o.x = f2bf((v.x-mean)*inv*gg.x + bb.x);
  o.y = f2bf((v.y-mean)*inv*gg.y + bb.y);
  o.z = f2bf((v.z-mean)*inv*gg.z + bb.z);
  o.w = f2bf((v.w-mean)*inv*gg.w + bb.w);
  ((ushort4*)(out + (size_t)m*256))[lane] = o;
}

// ---------------- GEMM: A[M][K] bf16 @ Bt[N][K] bf16, fp32 acc ----------------
// BM=128, BN=64, BK=32, 4 waves; wave computes 32x64 (2 m-frags x 4 n-frags).
// EPI 0: +bias(qkv concat), scatter q/k/v [win*8+head][64][32]
// EPI 1: +bo, window-reverse scatter, +hidden residual, fp32 out (hs)
// EPI 2: +b1, exact GELU, bf16 row-major out
// EPI 3: +b2, +hs residual, fp32 out
template<int EPI>
__global__ __launch_bounds__(256) void k_gemm(const u16* __restrict__ A, const u16* __restrict__ Bt,
                                              const float* __restrict__ bias, const float* __restrict__ res,
                                              void* __restrict__ outp, int K){
  __shared__ __align__(16) u16 As[128*32];
  __shared__ __align__(16) u16 Bs[64*32];
  int tid = threadIdx.x, lane = tid & 63, wid = tid >> 6;
  int g = lane >> 4, lr = lane & 15;
  int n0 = blockIdx.x*64, m0 = blockIdx.y*128;
  int arow = tid >> 2, acol = (tid & 3)*8;
  f32x4 acc[2][4] = {};
  for (int k0 = 0; k0 < K; k0 += 32){
    __syncthreads();
    *(uint4*)(As + arow*32 + acol)      = *(const uint4*)(A + (size_t)(m0+arow)*K + k0 + acol);
    *(uint4*)(As + (arow+64)*32 + acol) = *(const uint4*)(A + (size_t)(m0+arow+64)*K + k0 + acol);
    *(uint4*)(Bs + arow*32 + acol)      = *(const uint4*)(Bt + (size_t)(n0+arow)*K + k0 + acol);
    __syncthreads();
    bf16x8 a0 = *(const bf16x8*)(As + (wid*32 + lr)*32 + 8*g);
    bf16x8 a1 = *(const bf16x8*)(As + (wid*32 + 16 + lr)*32 + 8*g);
#pragma unroll
    for (int nj=0; nj<4; nj++){
      bf16x8 bf = *(const bf16x8*)(Bs + (nj*16 + lr)*32 + 8*g);
      acc[0][nj] = MFMA_BF16(a0, bf, acc[0][nj], 0,0,0);
      acc[1][nj] = MFMA_BF16(a1, bf, acc[1][nj], 0,0,0);
    }
  }
#pragma unroll
  for (int mi=0; mi<2; mi++)
#pragma unroll
  for (int nj=0; nj<4; nj++)
#pragma unroll
  for (int r=0; r<4; r++){
    int m = m0 + wid*32 + mi*16 + 4*g + r;
    int n = n0 + nj*16 + lr;
    float val = acc[mi][nj][r] + bias[n];
    if constexpr (EPI==0){
      int sec = n >> 8, ch = n & 255;
      size_t off = (size_t)sec*33554432u
                 + (((size_t)((m >> 6)*8 + (ch >> 5)))*64 + (m & 63))*32 + (ch & 31);
      ((u16*)outp)[off] = f2bf(val);
    } else if constexpr (EPI==1){
      int bi = m >> 12, win = (m >> 6) & 63, p = m & 63;
      int hh = ((win >> 3)*8 + (p >> 3) + 4) & 63;
      int ww = ((win & 7)*8 + (p & 7) + 4) & 63;
      size_t tok = (size_t)bi*4096 + hh*64 + ww;
      ((float*)outp)[tok*256 + n] = val + res[tok*256 + n];
    } else if constexpr (EPI==2){
      float gv = 0.5f*val*(1.f + erff(val*0.70710678118654752f));
      ((u16*)outp)[(size_t)m*1024 + n] = f2bf(gv);
    } else {
      ((float*)outp)[(size_t)m*256 + n] = val + res[(size_t)m*256 + n];
    }
  }
}

// ---------------- attention: one wave per (window, head) ----------------
// q,k,v each [2048*8][64][32] bf16. S = qk^T*scale + bias + mask, softmax,
// P (bf16, LDS) @ v -> out [131072][256] bf16 (head-merged).
__global__ __launch_bounds__(256) void k_attn(const u16* __restrict__ qkv, const float* __restrict__ btab,
                                              u16* __restrict__ outp){
  __shared__ __align__(16) u16 P[4][64*64];
  int lane = threadIdx.x & 63, wid = threadIdx.x >> 6;
  int g = lane >> 4, lr = lane & 15;
  int gw = blockIdx.x*4 + wid;
  int widx = gw >> 3, hh = gw & 7;
  const u16* qb = qkv + (size_t)(widx*8 + hh)*2048;
  const u16* kb = qb + 33554432u;
  const u16* vb = qb + 67108864u;
  bf16x8 qf[4], kf[4];
#pragma unroll
  for (int i=0;i<4;i++){
    qf[i] = *(const bf16x8*)(qb + (i*16 + lr)*32 + 8*g);
    kf[i] = *(const bf16x8*)(kb + (i*16 + lr)*32 + 8*g);
  }
  f32x4 acc[4][4] = {};
#pragma unroll
  for (int mi=0;mi<4;mi++)
#pragma unroll
  for (int nj=0;nj<4;nj++)
    acc[mi][nj] = MFMA_BF16(qf[mi], kf[nj], acc[mi][nj], 0,0,0);

  int win = widx & 63, wh = win >> 3, ww = win & 7;
  const float scale = 0.1767766952966369f; // 32^-0.5
#pragma unroll
  for (int mi=0;mi<4;mi++)
#pragma unroll
  for (int nj=0;nj<4;nj++)
#pragma unroll
  for (int r=0;r<4;r++){
    int m = mi*16 + 4*g + r, n = nj*16 + lr;
    int r1=m>>3, c1=m&7, r2=n>>3, c2=n&7;
    float bv = btab[((r1-r2+7)*15 + (c1-c2+7))*8 + hh];
    float mv = 0.f;
    if (wh==7 || ww==7){
      int a1 = (wh==7 ? (r1<4?1:2) : 0)*3 + (ww==7 ? (c1<4?1:2) : 0);
      int a2 = (wh==7 ? (r2<4?1:2) : 0)*3 + (ww==7 ? (c2<4?1:2) : 0);
      if (a1 != a2) mv = -100.f;
    }
    acc[mi][nj][r] = acc[mi][nj][r]*scale + bv + mv;
  }
  // softmax per row (row lives in one 16-lane group, 4 regs across nj)
#pragma unroll
  for (int mi=0;mi<4;mi++)
#pragma unroll
  for (int r=0;r<4;r++){
    float mx = fmaxf(fmaxf(acc[mi][0][r], acc[mi][1][r]), fmaxf(acc[mi][2][r], acc[mi][3][r]));
    for (int off=1; off<16; off<<=1) mx = fmaxf(mx, __shfl_xor(mx, off));
    float s = 0.f;
#pragma unroll
    for (int nj=0;nj<4;nj++){ float e = expf(acc[mi][nj][r]-mx); acc[mi][nj][r]=e; s+=e; }
    for (int off=1; off<16; off<<=1) s += __shfl_xor(s, off);
    float inv = 1.f/s;
#pragma unroll
    for (int nj=0;nj<4;nj++) acc[mi][nj][r] *= inv;
  }
  u16* Pw = P[wid];
#pragma unroll
  for (int mi=0;mi<4;mi++)
#pragma unroll
  for (int nj=0;nj<4;nj++)
#pragma unroll
  for (int r=0;r<4;r++)
    Pw[(mi*16+4*g+r)*64 + nj*16 + lr] = f2bf(acc[mi][nj][r]);
  __syncthreads();

  f32x4 acc2[4][2] = {};
#pragma unroll
  for (int ks=0; ks<2; ks++){
    bf16x8 vf[2];
#pragma unroll
    for (int nt=0; nt<2; nt++)
#pragma unroll
      for (int i=0;i<8;i++)
        vf[nt][i] = (short)vb[(ks*32 + 8*g + i)*32 + nt*16 + lr];
#pragma unroll
    for (int mi=0;mi<4;mi++){
      bf16x8 pf = *(const bf16x8*)(Pw + (mi*16 + lr)*64 + ks*32 + 8*g);
      acc2[mi][0] = MFMA_BF16(pf, vf[0], acc2[mi][0], 0,0,0);
      acc2[mi][1] = MFMA_BF16(pf, vf[1], acc2[mi][1], 0,0,0);
    }
  }
#pragma unroll
  for (int mi=0;mi<4;mi++)
#pragma unroll
  for (int nt=0;nt<2;nt++)
#pragma unroll
  for (int r=0;r<4;r++)
    outp[((size_t)widx*64 + mi*16+4*g+r)*256 + hh*32 + nt*16 + lr] = f2bf(acc2[mi][nt][r]);
}

extern "C" void kernel_launch(void* const* d_in, const int* in_sizes, int n_in,
                              void* d_out, int out_size, void* d_ws, size_t ws_size,
                              hipStream_t stream){
  const float* hidden = (const float*)d_in[0];
  const float* ln1g = (const float*)d_in[1];
  const float* ln1b = (const float*)d_in[2];
  const float* wq   = (const float*)d_in[3];
  const float* bq   = (const float*)d_in[4];
  const float* wk   = (const float*)d_in[5];
  const float* bk   = (const float*)d_in[6];
  const float* wv   = (const float*)d_in[7];
  const float* bv   = (const float*)d_in[8];
  const float* btab = (const float*)d_in[9];
  const float* wo   = (const float*)d_in[10];
  const float* bo   = (const float*)d_in[11];
  const float* ln2g = (const float*)d_in[12];
  const float* ln2b = (const float*)d_in[13];
  const float* w1   = (const float*)d_in[14];
  const float* b1   = (const float*)d_in[15];
  const float* w2   = (const float*)d_in[16];
  const float* b2   = (const float*)d_in[17];
  float* out = (float*)d_out;

  char* ws = (char*)d_ws;
  const size_t MB = 1ull << 20;
  u16* xw    = (u16*)ws;                 // [0,64M): xw -> attn_out -> y (reused)
  u16* qkv   = (u16*)(ws + 64*MB);       // [64M,256M): q|k|v ; later y1 chunk reuses [64M,128M)
  u16* y1c   = qkv;
  u16* wqkvT = (u16*)(ws + 256*MB);      // bf16 weights, transposed [N][K]
  u16* woT   = wqkvT + 768*256;
  u16* w1T   = woT + 256*256;
  u16* w2T   = w1T + 1024*256;
  float* bqkv = (float*)(w2T + 1024*256);

  // weight prep
  k_transpose<<<256, 256, 0, stream>>>(wq, wqkvT,          256, 256);
  k_transpose<<<256, 256, 0, stream>>>(wk, wqkvT + 65536,  256, 256);
  k_transpose<<<256, 256, 0, stream>>>(wv, wqkvT + 131072, 256, 256);
  k_transpose<<<256, 256, 0, stream>>>(wo, woT,            256, 256);
  k_transpose<<<1024,256, 0, stream>>>(w1, w1T,            256, 1024);
  k_transpose<<<1024,256, 0, stream>>>(w2, w2T,            1024, 256);
  k_concat_bias<<<1, 768, 0, stream>>>(bq, bk, bv, bqkv);

  // LN1 + shift + window partition
  k_ln1<<<32768, 256, 0, stream>>>(hidden, ln1g, ln1b, xw);
  // QKV projection
  k_gemm<0><<<dim3(12, 1024), 256, 0, stream>>>(xw, wqkvT, bqkv, nullptr, qkv, 256);
  // windowed attention (attn_out into xw region)
  k_attn<<<4096, 256, 0, stream>>>(qkv, btab, xw);
  // O-projection + window reverse + residual -> hs (stored in d_out)
  k_gemm<1><<<dim3(4, 1024), 256, 0, stream>>>(xw, woT, bo, hidden, out, 256);
  // LN2 -> y (xw region)
  k_ln2<<<32768, 256, 0, stream>>>(out, ln2g, ln2b, xw);
  // MLP in 4 M-chunks of 32768 rows (y1 reuses dead qkv region)
  for (int mc = 0; mc < 4; mc++){
    k_gemm<2><<<dim3(16, 256), 256, 0, stream>>>(xw + (size_t)mc*32768*256, w1T, b1, nullptr, y1c, 256);
    k_gemm<3><<<dim3(4, 256), 256, 0, stream>>>(y1c, w2T, b2,
                                                out + (size_t)mc*32768*256,
                                                out + (size_t)mc*32768*256, 1024);
  }
}

// Round 2
// 744.949 us; speedup vs baseline: 1.1618x; 1.1618x over previous
//
#include <hip/hip_runtime.h>
#include <hip/hip_bf16.h>
#include <math.h>

typedef unsigned short u16;
typedef __attribute__((ext_vector_type(8))) short bf16x8;
typedef __attribute__((ext_vector_type(4))) float f32x4;

#define MFMA_BF16 __builtin_amdgcn_mfma_f32_16x16x32_bf16

__device__ __forceinline__ u16 f2bf(float f){
  union { float f; unsigned u; } v; v.f = f;
  unsigned r = v.u + 0x7FFFu + ((v.u >> 16) & 1u);
  return (u16)(r >> 16);
}

__device__ __forceinline__ void gll16(const void* g, void* l){
  __builtin_amdgcn_global_load_lds(
      (const __attribute__((address_space(1))) unsigned int*)g,
      (__attribute__((address_space(3))) unsigned int*)l, 16, 0, 0);
}

// ---------------- weight prep: fp32 [K][N] -> bf16 [N][K] ----------------
__global__ void k_transpose(const float* __restrict__ src, u16* __restrict__ dst, int K, int N){
  int idx = blockIdx.x*256 + threadIdx.x;
  if (idx >= K*N) return;
  int n = idx / K, k = idx - n*K;
  dst[idx] = f2bf(src[(size_t)k*N + n]);
}

__global__ void k_concat_bias(const float* __restrict__ a, const float* __restrict__ b,
                              const float* __restrict__ c, float* __restrict__ o){
  int i = threadIdx.x;  // 768 threads
  o[i] = i < 256 ? a[i] : (i < 512 ? b[i-256] : c[i-512]);
}

// ---- fused rel-pos bias + shift mask table: fb[cls][head][m][n] ----
// cls bit1: window on bottom edge (wh==7), bit0: right edge (ww==7)
__global__ __launch_bounds__(256) void k_bias(const float* __restrict__ btab, float* __restrict__ fb){
  int idx = blockIdx.x*256 + threadIdx.x;   // 4*8*64*64 = 131072
  int n = idx & 63, m = (idx >> 6) & 63, hh = (idx >> 12) & 7, cls = idx >> 15;
  int r1=m>>3, c1=m&7, r2=n>>3, c2=n&7;
  float bv = btab[((r1-r2+7)*15 + (c1-c2+7))*8 + hh];
  int whe = cls>>1, wwe = cls&1;
  int a1 = (whe ? (r1<4?1:2) : 0)*3 + (wwe ? (c1<4?1:2) : 0);
  int a2 = (whe ? (r2<4?1:2) : 0)*3 + (wwe ? (c2<4?1:2) : 0);
  fb[idx] = bv + ((a1!=a2) ? -100.f : 0.f);
}

// ------------- LN1 + cyclic shift + window partition -> bf16 -------------
__global__ __launch_bounds__(256) void k_ln1(const float* __restrict__ x, const float* __restrict__ g,
                                             const float* __restrict__ b, u16* __restrict__ out){
  int lane = threadIdx.x & 63;
  int m = blockIdx.x*4 + (threadIdx.x >> 6);
  int bi = m >> 12, win = (m >> 6) & 63, p = m & 63;
  int h = ((win >> 3)*8 + (p >> 3) + 4) & 63;
  int w = ((win & 7)*8 + (p & 7) + 4) & 63;
  float4 v = ((const float4*)(x + ((size_t)bi*4096 + h*64 + w)*256))[lane];
  float s = v.x+v.y+v.z+v.w, sq = v.x*v.x+v.y*v.y+v.z*v.z+v.w*v.w;
  for (int off=32; off; off>>=1){ s += __shfl_xor(s, off); sq += __shfl_xor(sq, off); }
  float mean = s*(1.f/256.f);
  float inv = rsqrtf(sq*(1.f/256.f) - mean*mean + 1e-5f);
  float4 gg = ((const float4*)g)[lane], bb = ((const float4*)b)[lane];
  ushort4 o;
  o.x = f2bf((v.x-mean)*inv*gg.x + bb.x);
  o.y = f2bf((v.y-mean)*inv*gg.y + bb.y);
  o.z = f2bf((v.z-mean)*inv*gg.z + bb.z);
  o.w = f2bf((v.w-mean)*inv*gg.w + bb.w);
  ((ushort4*)(out + (size_t)m*256))[lane] = o;
}

// ---------------- LN2 (no gather) -> bf16 ----------------
__global__ __launch_bounds__(256) void k_ln2(const float* __restrict__ x, const float* __restrict__ g,
                                             const float* __restrict__ b, u16* __restrict__ out){
  int lane = threadIdx.x & 63;
  int m = blockIdx.x*4 + (threadIdx.x >> 6);
  float4 v = ((const float4*)(x + (size_t)m*256))[lane];
  float s = v.x+v.y+v.z+v.w, sq = v.x*v.x+v.y*v.y+v.z*v.z+v.w*v.w;
  for (int off=32; off; off>>=1){ s += __shfl_xor(s, off); sq += __shfl_xor(sq, off); }
  float mean = s*(1.f/256.f);
  float inv = rsqrtf(sq*(1.f/256.f) - mean*mean + 1e-5f);
  float4 gg = ((const float4*)g)[lane], bb = ((const float4*)b)[lane];
  ushort4 o;
  o.x = f2bf((v.x-mean)*inv*gg.x + bb.x);
  o.y = f2bf((v.y-mean)*inv*gg.y + bb.y);
  o.z = f2bf((v.z-mean)*inv*gg.z + bb.z);
  o.w = f2bf((v.w-mean)*inv*gg.w + bb.w);
  ((ushort4*)(out + (size_t)m*256))[lane] = o;
}

// ---------------- GEMM: A[M][K] bf16 @ Bt[N][K] bf16, fp32 acc ----------------
// m97 structure: BM=BN=128, BK=64, 4 waves (2x2, 64x64 each), global_load_lds.
// EPI 0: +bias(qkv concat), q scaled, scatter q/k [wh][tok][dim], v TRANSPOSED [wh][dim][tok]
// EPI 1: +bo, window-reverse scatter, +hidden residual, fp32 out (hs)
// EPI 2: +b1, exact GELU, bf16 row-major out
// EPI 3: +b2, +hs residual, fp32 out
template<int EPI>
__global__ __launch_bounds__(256) void k_gemm(const u16* __restrict__ A, const u16* __restrict__ Bt,
                                              const float* __restrict__ bias, const float* __restrict__ res,
                                              void* __restrict__ outp, int K){
  __shared__ __align__(16) u16 As[128*64];
  __shared__ __align__(16) u16 Bs[128*64];
  int tid = threadIdx.x, lane = tid & 63, wid = tid >> 6;
  int g = lane >> 4, lr = lane & 15;
  int wr = wid >> 1, wc = wid & 1;
  int m0 = blockIdx.y*128, n0 = blockIdx.x*128;
  const u16* Aw = A + (size_t)m0*K;
  const u16* Bw = Bt + (size_t)n0*K;
  int srow = (lane >> 3);        // 0..7 within chunk
  int scol = (lane & 7)*8;       // u16 col within 64
  f32x4 acc[4][4] = {};
  for (int k0 = 0; k0 < K; k0 += 64){
    __syncthreads();
#pragma unroll
    for (int c = 0; c < 4; c++){
      int chunk = wid*4 + c;           // 0..15, 8 rows each
      int row = chunk*8 + srow;
      gll16(Aw + (size_t)row*K + k0 + scol, As + chunk*512);
      gll16(Bw + (size_t)row*K + k0 + scol, Bs + chunk*512);
    }
    __syncthreads();
#pragma unroll
    for (int kk = 0; kk < 2; kk++){
      bf16x8 af[4], bf[4];
#pragma unroll
      for (int i=0;i<4;i++){
        af[i] = *(const bf16x8*)(As + (wr*64 + i*16 + lr)*64 + kk*32 + 8*g);
        bf[i] = *(const bf16x8*)(Bs + (wc*64 + i*16 + lr)*64 + kk*32 + 8*g);
      }
#pragma unroll
      for (int mi=0;mi<4;mi++)
#pragma unroll
      for (int nj=0;nj<4;nj++)
        acc[mi][nj] = MFMA_BF16(af[mi], bf[nj], acc[mi][nj], 0,0,0);
    }
  }
  const float scale = 0.1767766952966369f; // 32^-0.5
#pragma unroll
  for (int mi=0; mi<4; mi++)
#pragma unroll
  for (int nj=0; nj<4; nj++){
    int n = n0 + wc*64 + nj*16 + lr;
    if constexpr (EPI==0){
      int sec = n >> 8, ch = n & 255, head = ch >> 5, dim = ch & 31;
      if (sec < 2){
#pragma unroll
        for (int r=0; r<4; r++){
          int m = m0 + wr*64 + mi*16 + 4*g + r;
          float val = acc[mi][nj][r] + bias[n];
          if (sec == 0) val *= scale;
          size_t off = (size_t)sec*33554432u
                     + (((size_t)((m >> 6)*8 + head))*64 + (m & 63))*32 + dim;
          ((u16*)outp)[off] = f2bf(val);
        }
      } else {
        ushort4 pack;
        float bv = bias[n];
        pack.x = f2bf(acc[mi][nj][0] + bv);
        pack.y = f2bf(acc[mi][nj][1] + bv);
        pack.z = f2bf(acc[mi][nj][2] + bv);
        pack.w = f2bf(acc[mi][nj][3] + bv);
        int m_ = m0 + wr*64 + mi*16 + 4*g;
        size_t off = (size_t)2*33554432u
                   + (((size_t)((m_ >> 6)*8 + head))*32 + dim)*64 + (m_ & 63);
        *(ushort4*)((u16*)outp + off) = pack;
      }
    } else {
#pragma unroll
      for (int r=0; r<4; r++){
        int m = m0 + wr*64 + mi*16 + 4*g + r;
        float val = acc[mi][nj][r] + bias[n];
        if constexpr (EPI==1){
          int bi = m >> 12, win = (m >> 6) & 63, p = m & 63;
          int hh = ((win >> 3)*8 + (p >> 3) + 4) & 63;
          int ww = ((win & 7)*8 + (p & 7) + 4) & 63;
          size_t tok = (size_t)bi*4096 + hh*64 + ww;
          ((float*)outp)[tok*256 + n] = val + res[tok*256 + n];
        } else if constexpr (EPI==2){
          float gv = 0.5f*val*(1.f + erff(val*0.70710678118654752f));
          ((u16*)outp)[(size_t)m*1024 + n] = f2bf(gv);
        } else {
          ((float*)outp)[(size_t)m*256 + n] = val + res[(size_t)m*256 + n];
        }
      }
    }
  }
}

// ---------------- attention: one wave per (window, head) ----------------
// q,k: [2048*8][64][32] bf16 (q pre-scaled); v: [2048*8][32][64] (transposed).
// S = qk^T + fb[cls][head], softmax, P (bf16, swizzled LDS) @ v -> out bf16.
__global__ __launch_bounds__(256) void k_attn(const u16* __restrict__ qkv, const float* __restrict__ fb,
                                              u16* __restrict__ outp){
  __shared__ __align__(16) u16 P[4][64*64];
  int lane = threadIdx.x & 63, wid = threadIdx.x >> 6;
  int g = lane >> 4, lr = lane & 15;
  int gw = blockIdx.x*4 + wid;
  int widx = gw >> 3, hh = gw & 7;
  const u16* qb = qkv + (size_t)(widx*8 + hh)*2048;
  const u16* kb = qb + 33554432u;
  const u16* vt = qb + 67108864u;
  bf16x8 qf[4], kf[4];
#pragma unroll
  for (int i=0;i<4;i++){
    qf[i] = *(const bf16x8*)(qb + (i*16 + lr)*32 + 8*g);
    kf[i] = *(const bf16x8*)(kb + (i*16 + lr)*32 + 8*g);
  }
  f32x4 acc[4][4] = {};
#pragma unroll
  for (int mi=0;mi<4;mi++)
#pragma unroll
  for (int nj=0;nj<4;nj++)
    acc[mi][nj] = MFMA_BF16(qf[mi], kf[nj], acc[mi][nj], 0,0,0);

  int win = widx & 63;
  int cls = (((win>>3)==7) ? 2 : 0) | (((win&7)==7) ? 1 : 0);
  const float* fbh = fb + (((size_t)cls*8 + hh) << 12);
#pragma unroll
  for (int mi=0;mi<4;mi++)
#pragma unroll
  for (int r=0;r<4;r++){
    int m = mi*16 + 4*g + r;
#pragma unroll
    for (int nj=0;nj<4;nj++)
      acc[mi][nj][r] += fbh[m*64 + nj*16 + lr];
  }
  // softmax per row (row lives in one 16-lane group, 4 regs across nj)
#pragma unroll
  for (int mi=0;mi<4;mi++)
#pragma unroll
  for (int r=0;r<4;r++){
    float mx = fmaxf(fmaxf(acc[mi][0][r], acc[mi][1][r]), fmaxf(acc[mi][2][r], acc[mi][3][r]));
    for (int off=1; off<16; off<<=1) mx = fmaxf(mx, __shfl_xor(mx, off));
    float s = 0.f;
#pragma unroll
    for (int nj=0;nj<4;nj++){ float e = __expf(acc[mi][nj][r]-mx); acc[mi][nj][r]=e; s+=e; }
    for (int off=1; off<16; off<<=1) s += __shfl_xor(s, off);
    float inv = 1.f/s;
#pragma unroll
    for (int nj=0;nj<4;nj++) acc[mi][nj][r] *= inv;
  }
  // P -> LDS, XOR-swizzled at 8-u16 (16B) blocks: blk ^= row&7
  u16* Pw = P[wid];
#pragma unroll
  for (int mi=0;mi<4;mi++)
#pragma unroll
  for (int nj=0;nj<4;nj++)
#pragma unroll
  for (int r=0;r<4;r++){
    int row = mi*16 + 4*g + r;
    int blk = (nj*2 + (lr>>3)) ^ (row & 7);
    Pw[row*64 + blk*8 + (lr&7)] = f2bf(acc[mi][nj][r]);
  }
  __syncthreads();

  f32x4 acc2[4][2] = {};
#pragma unroll
  for (int ks=0; ks<2; ks++){
    bf16x8 vf[2];
#pragma unroll
    for (int nt=0; nt<2; nt++)
      vf[nt] = *(const bf16x8*)(vt + (nt*16 + lr)*64 + ks*32 + 8*g);
#pragma unroll
    for (int mi=0;mi<4;mi++){
      int row = mi*16 + lr;
      int blk = (ks*4 + g) ^ (row & 7);
      bf16x8 pf = *(const bf16x8*)(Pw + row*64 + blk*8);
      acc2[mi][0] = MFMA_BF16(pf, vf[0], acc2[mi][0], 0,0,0);
      acc2[mi][1] = MFMA_BF16(pf, vf[1], acc2[mi][1], 0,0,0);
    }
  }
#pragma unroll
  for (int mi=0;mi<4;mi++)
#pragma unroll
  for (int nt=0;nt<2;nt++)
#pragma unroll
  for (int r=0;r<4;r++)
    outp[((size_t)widx*64 + mi*16+4*g+r)*256 + hh*32 + nt*16 + lr] = f2bf(acc2[mi][nt][r]);
}

extern "C" void kernel_launch(void* const* d_in, const int* in_sizes, int n_in,
                              void* d_out, int out_size, void* d_ws, size_t ws_size,
                              hipStream_t stream){
  const float* hidden = (const float*)d_in[0];
  const float* ln1g = (const float*)d_in[1];
  const float* ln1b = (const float*)d_in[2];
  const float* wq   = (const float*)d_in[3];
  const float* bq   = (const float*)d_in[4];
  const float* wk   = (const float*)d_in[5];
  const float* bk   = (const float*)d_in[6];
  const float* wv   = (const float*)d_in[7];
  const float* bv   = (const float*)d_in[8];
  const float* btab = (const float*)d_in[9];
  const float* wo   = (const float*)d_in[10];
  const float* bo   = (const float*)d_in[11];
  const float* ln2g = (const float*)d_in[12];
  const float* ln2b = (const float*)d_in[13];
  const float* w1   = (const float*)d_in[14];
  const float* b1   = (const float*)d_in[15];
  const float* w2   = (const float*)d_in[16];
  const float* b2   = (const float*)d_in[17];
  float* out = (float*)d_out;

  char* ws = (char*)d_ws;
  const size_t MB = 1ull << 20;
  u16* xw    = (u16*)ws;                 // [0,64M): xw -> attn_out -> y (reused)
  u16* qkv   = (u16*)(ws + 64*MB);       // [64M,256M): q|k|v ; later y1 chunk reuses [64M,128M)
  u16* y1c   = qkv;
  u16* wqkvT = (u16*)(ws + 256*MB);      // bf16 weights, transposed [N][K]
  u16* woT   = wqkvT + 768*256;
  u16* w1T   = woT + 256*256;
  u16* w2T   = w1T + 1024*256;
  float* bqkv = (float*)(w2T + 1024*256);
  float* fbias = bqkv + 1024;            // 4*8*64*64 fp32 = 512KB

  // weight prep
  k_transpose<<<256, 256, 0, stream>>>(wq, wqkvT,          256, 256);
  k_transpose<<<256, 256, 0, stream>>>(wk, wqkvT + 65536,  256, 256);
  k_transpose<<<256, 256, 0, stream>>>(wv, wqkvT + 131072, 256, 256);
  k_transpose<<<256, 256, 0, stream>>>(wo, woT,            256, 256);
  k_transpose<<<1024,256, 0, stream>>>(w1, w1T,            256, 1024);
  k_transpose<<<1024,256, 0, stream>>>(w2, w2T,            1024, 256);
  k_concat_bias<<<1, 768, 0, stream>>>(bq, bk, bv, bqkv);
  k_bias<<<512, 256, 0, stream>>>(btab, fbias);

  // LN1 + shift + window partition
  k_ln1<<<32768, 256, 0, stream>>>(hidden, ln1g, ln1b, xw);
  // QKV projection
  k_gemm<0><<<dim3(6, 1024), 256, 0, stream>>>(xw, wqkvT, bqkv, nullptr, qkv, 256);
  // windowed attention (attn_out into xw region)
  k_attn<<<4096, 256, 0, stream>>>(qkv, fbias, xw);
  // O-projection + window reverse + residual -> hs (stored in d_out)
  k_gemm<1><<<dim3(2, 1024), 256, 0, stream>>>(xw, woT, bo, hidden, out, 256);
  // LN2 -> y (xw region)
  k_ln2<<<32768, 256, 0, stream>>>(out, ln2g, ln2b, xw);
  // MLP in 4 M-chunks of 32768 rows (y1 reuses dead qkv region)
  for (int mc = 0; mc < 4; mc++){
    k_gemm<2><<<dim3(8, 256), 256, 0, stream>>>(xw + (size_t)mc*32768*256, w1T, b1, nullptr, y1c, 256);
    k_gemm<3><<<dim3(2, 256), 256, 0, stream>>>(y1c, w2T, b2,
                                                out + (size_t)mc*32768*256,
                                                out + (size_t)mc*32768*256, 1024);
  }
}